// Round 4
// baseline (158.511 us; speedup 1.0000x reference)
//
#include <hip/hip_runtime.h>

// BatchIndependentLoss: SupCon-style loss, B=2048, V=2, D=256, N=4096.
// loss = -mean_i( lp_i - (W_i - e^{lp}*lp) / u_new[i%B] )
// R4 structure: NO LDS, NO barriers in the GEMM K-loop. The 2 MB bf16
// operand is L2-resident; prep re-packs it fragment-major so each wave's
// MFMA fragment load is one fully-coalesced 1 KB global_load_dwordx4.
// One wave = one independent 64x64 tile of the upper triangle (2080 tiles,
// 520 blocks x 4 waves), software-pipelined loads (depth 1), fused stats +
// last-block ticket finalize. R3 was 66 us with all pipes <7% busy:
// barrier-serialized staging at 2 blocks/CU. This removes the barriers.
//
// CmF layout: shorts, index = ((band*8 + k)*4 + rt)*512 + (l15*4+quad)*8 + j
//   band = row>>6, rt = (row>>4)&3, l15 = row&15, k = kelem>>5,
//   quad = (kelem>>3)&3, j = kelem&7.
// Fragment load for (tileband, k, rt): wave lanes (quad,l15) read 16 B at
//   base + ((band*8+k)*4+rt)*512 + (l15*4+quad)*8  -> contiguous 1 KB/wave.

#define BSZ   2048
#define NROW  4096
#define DDIM  256
#define INVT  (1.0f / 0.07f)
#define NB64  64                     // 4096/64 bands
#define NT2   (NB64 * (NB64 + 1) / 2)  // 2080 upper-triangle 64x64 tiles
#define TPB   4                      // tiles (waves) per block
#define NBLK  (NT2 / TPB)            // 520 blocks

typedef __attribute__((ext_vector_type(8))) __bf16 bf16x8;
typedef __attribute__((ext_vector_type(4))) float f32x4;

__device__ __forceinline__ short f2bs(float x) {
    __bf16 b = (__bf16)x;
    return __builtin_bit_cast(short, b);
}
__device__ __forceinline__ void ag_store(float* p, float v) {
    __hip_atomic_store(p, v, __ATOMIC_RELAXED, __HIP_MEMORY_SCOPE_AGENT);
}
__device__ __forceinline__ float ag_load(const float* p) {
    return __hip_atomic_load(p, __ATOMIC_RELAXED, __HIP_MEMORY_SCOPE_AGENT);
}

// contrast row i = v*B + b  ->  features row b*V + v  (fp32, 256 elems)
__device__ __forceinline__ const float* crow_ptr(const float* feats, int i) {
    return feats + (((i & (BSZ - 1)) * 2 + (i >> 11)) << 8);
}

// ---------------- prep: frag-major bf16 pack, self-dots, zero E/W/cnt ------
__global__ __launch_bounds__(256) void prep_kernel(const float* __restrict__ feats,
        float* __restrict__ selfdot, float* __restrict__ EWzero,
        int* __restrict__ cnt, short* __restrict__ CmF) {
    int tid = threadIdx.x;
    int z = blockIdx.x * 256 + tid;
    if (z < 2 * NROW) EWzero[z] = 0.0f;                  // zero E and W
    if (z == 0) __hip_atomic_store(cnt, 0, __ATOMIC_RELAXED, __HIP_MEMORY_SCOPE_AGENT);

    // --- part A: self-dot, one wave per row (1024 blocks x 4 waves) ---
    int lane = tid & 63;
    int row  = (blockIdx.x << 2) + (tid >> 6);
    const float4* src = (const float4*)crow_ptr(feats, row);
    float4 v = src[lane];
    float a0 = (float)(__bf16)v.x, a1 = (float)(__bf16)v.y;
    float a2 = (float)(__bf16)v.z, a3 = (float)(__bf16)v.w;
    float s = a0 * a0 + a1 * a1 + a2 * a2 + a3 * a3;     // self-dot of bf16 row
    #pragma unroll
    for (int off = 32; off; off >>= 1) s += __shfl_xor(s, off, 64);
    if (lane == 0) selfdot[row] = s;

    // --- part B: fragment-major pack; gid covers 2M shorts / 8 per thread ---
    int gid  = z;                    // 0..262143
    int quad = gid & 3;
    int l15  = (gid >> 2) & 15;
    int rt   = (gid >> 6) & 3;
    int k    = (gid >> 8) & 7;
    int b    = gid >> 12;
    int srow = (b << 6) + (rt << 4) + l15;
    int kel  = (k << 5) + (quad << 3);
    const float4* fp = (const float4*)(crow_ptr(feats, srow) + kel);
    float4 v0 = fp[0], v1 = fp[1];
    short h[8] = { f2bs(v0.x), f2bs(v0.y), f2bs(v0.z), f2bs(v0.w),
                   f2bs(v1.x), f2bs(v1.y), f2bs(v1.z), f2bs(v1.w) };
    *(int4*)(CmF + gid * 8) = *(int4*)h;
}

// ---------------- barrier-free symmetric GEMM + stats + finalize -----------
__global__ __launch_bounds__(256) void gemm_sym(const short* __restrict__ CmF,
        const float* __restrict__ selfdot, float* __restrict__ E,
        float* __restrict__ W, float* __restrict__ Lpos, int* __restrict__ cnt,
        const int* __restrict__ index, const float* __restrict__ u,
        float* __restrict__ out) {
    int tid  = threadIdx.x;
    int wave = tid >> 6;
    int lane = tid & 63;
    int quad = lane >> 4;
    int l15  = lane & 15;

    // one wave = one tile; triangle decode t -> (p,q), p>=q
    int t = blockIdx.x * TPB + wave;
    int p = (int)((sqrtf(8.0f * (float)t + 1.0f) - 1.0f) * 0.5f);
    while ((p + 1) * (p + 2) / 2 <= t) ++p;
    while (p * (p + 1) / 2 > t) --p;
    int q = t - p * (p + 1) / 2;
    int rowBase = q << 6;            // row band (64)
    int colBase = p << 6;            // col band, >= row band
    bool offdiag = (p != q);

    const short* aB = CmF + q * 16384 + ((l15 << 2) + quad) * 8;
    const short* bB = CmF + p * 16384 + ((l15 << 2) + quad) * 8;

    f32x4 acc[4][4];
    #pragma unroll
    for (int a = 0; a < 4; ++a)
        #pragma unroll
        for (int c = 0; c < 4; ++c) acc[a][c] = (f32x4){0.f, 0.f, 0.f, 0.f};

    bf16x8 aC[4], bC[4];
    #pragma unroll
    for (int rt = 0; rt < 4; ++rt) aC[rt] = *(const bf16x8*)(aB + rt * 512);
    #pragma unroll
    for (int ct = 0; ct < 4; ++ct) bC[ct] = *(const bf16x8*)(bB + ct * 512);

    #pragma unroll
    for (int k = 0; k < 8; ++k) {
        bf16x8 aN[4], bN[4];
        if (k < 7) {                 // prefetch next k-step (no barrier, stays in flight)
            #pragma unroll
            for (int rt = 0; rt < 4; ++rt)
                aN[rt] = *(const bf16x8*)(aB + ((k + 1) * 4 + rt) * 512);
            #pragma unroll
            for (int ct = 0; ct < 4; ++ct)
                bN[ct] = *(const bf16x8*)(bB + ((k + 1) * 4 + ct) * 512);
        }
        #pragma unroll
        for (int rt = 0; rt < 4; ++rt)
            #pragma unroll
            for (int ct = 0; ct < 4; ++ct)
                acc[rt][ct] = __builtin_amdgcn_mfma_f32_16x16x32_bf16(
                    aC[rt], bC[ct], acc[rt][ct], 0, 0, 0);
        if (k < 7) {
            #pragma unroll
            for (int rt = 0; rt < 4; ++rt) aC[rt] = aN[rt];
            #pragma unroll
            for (int ct = 0; ct < 4; ++ct) bC[ct] = bN[ct];
        }
    }

    // ---- epilogue: C/D layout col = lane&15, row = quad*4 + reg  [m89/m91]
    float sdr[4][4];
    #pragma unroll
    for (int rt = 0; rt < 4; ++rt)
        #pragma unroll
        for (int r = 0; r < 4; ++r)
            sdr[rt][r] = selfdot[rowBase + rt * 16 + (quad << 2) + r];
    float sdc[4];
    #pragma unroll
    for (int ct = 0; ct < 4; ++ct)
        sdc[ct] = selfdot[colBase + ct * 16 + l15];

    float Ep[4][4] = {}, Wp[4][4] = {};
    float Ec[4] = {}, Wc[4] = {};
    #pragma unroll
    for (int rt = 0; rt < 4; ++rt) {
        #pragma unroll
        for (int ct = 0; ct < 4; ++ct) {
            int gcol = colBase + ct * 16 + l15;
            #pragma unroll
            for (int r = 0; r < 4; ++r) {
                int grow = rowBase + rt * 16 + (quad << 2) + r;
                float d = acc[rt][ct][r];
                float l = (d - sdr[rt][r]) * INVT;       // row-view logit
                float e = __expf(l);
                Ep[rt][r] += e;
                Wp[rt][r] += e * l;
                if (gcol == (grow ^ BSZ)) ag_store(&Lpos[grow], l);
                if (offdiag) {
                    float l2 = (d - sdc[ct]) * INVT;     // col-view logit
                    float e2 = __expf(l2);
                    Ec[ct] += e2;
                    Wc[ct] += e2 * l2;
                    if (grow == (gcol ^ BSZ)) ag_store(&Lpos[gcol], l2);
                }
            }
        }
    }
    // row-path: reduce over 16 l15 lanes per row, 1-lane atomic per row
    #pragma unroll
    for (int rt = 0; rt < 4; ++rt) {
        #pragma unroll
        for (int r = 0; r < 4; ++r) {
            float e = Ep[rt][r], w = Wp[rt][r];
            #pragma unroll
            for (int off = 1; off < 16; off <<= 1) {
                e += __shfl_xor(e, off, 64);
                w += __shfl_xor(w, off, 64);
            }
            if (l15 == 0) {
                int grow = rowBase + rt * 16 + (quad << 2) + r;
                atomicAdd(&E[grow], e);
                atomicAdd(&W[grow], w);
            }
        }
    }
    // col-path: reduce over 4 quads per col, 16-lane atomic
    if (offdiag) {
        #pragma unroll
        for (int ct = 0; ct < 4; ++ct) {
            float e = Ec[ct], w = Wc[ct];
            e += __shfl_xor(e, 16, 64);  w += __shfl_xor(w, 16, 64);
            e += __shfl_xor(e, 32, 64);  w += __shfl_xor(w, 32, 64);
            if (quad == 0) {
                int gcol = colBase + ct * 16 + l15;
                atomicAdd(&E[gcol], e);
                atomicAdd(&W[gcol], w);
            }
        }
    }

    // ---- last-block ticket: fused finalize ----
    __shared__ int isLast;
    __threadfence();                 // release our E/W/Lpos writes
    __syncthreads();
    if (tid == 0) isLast = (atomicAdd(cnt, 1) == NBLK - 1);
    __syncthreads();
    if (!isLast) return;
    __threadfence();                 // acquire all blocks' writes

    __shared__ float unew[BSZ];
    for (int b = tid; b < BSZ; b += 256) {
        float lp = ag_load(&Lpos[b]);
        unew[b] = 0.1f * u[index[b]] + 0.9f * (ag_load(&E[b]) - __expf(lp));
    }
    __syncthreads();
    float local = 0.0f;
    for (int i = tid; i < NROW; i += 256) {
        float lp  = ag_load(&Lpos[i]);
        float elp = __expf(lp);
        local += lp - (ag_load(&W[i]) - elp * lp) / unew[i & (BSZ - 1)];
    }
    #pragma unroll
    for (int off = 32; off; off >>= 1) local += __shfl_xor(local, off, 64);
    __shared__ float part[4];
    if (lane == 0) part[wave] = local;
    __syncthreads();
    if (tid == 0) out[0] = -(part[0] + part[1] + part[2] + part[3]) / (float)NROW;
}

extern "C" void kernel_launch(void* const* d_in, const int* in_sizes, int n_in,
                              void* d_out, int out_size, void* d_ws, size_t ws_size,
                              hipStream_t stream) {
    const int*   index = (const int*)d_in[0];
    const float* feats = (const float*)d_in[1];
    const float* u     = (const float*)d_in[2];
    float* out = (float*)d_out;

    // ws: [selfdot|E|W|Lpos] (4x4096 f32 = 64 KB) | cnt | ... | CmF @128KB
    float* selfdot = (float*)d_ws;
    float* E    = selfdot + NROW;
    float* W    = E + NROW;
    float* Lpos = W + NROW;
    int*   cnt  = (int*)(Lpos + NROW);                   // byte 65536
    short* CmF  = (short*)((char*)d_ws + 131072);        // byte 131072, 2 MB

    prep_kernel<<<1024, 256, 0, stream>>>(feats, selfdot, E, cnt, CmF);
    gemm_sym<<<NBLK, 256, 0, stream>>>(CmF, selfdot, E, W, Lpos, cnt, index, u, out);
}

// Round 5
// 147.932 us; speedup vs baseline: 1.0715x; 1.0715x over previous
//
#include <hip/hip_runtime.h>

// BatchIndependentLoss: SupCon-style loss, B=2048, V=2, D=256, N=4096.
// loss = -mean_i( lp_i - (W_i - e^{lp}*lp) / u_new[i%B] )
// Structure (R4): NO LDS, NO barriers in the GEMM K-loop; 2 MB frag-major
// bf16 operand is L2-resident; one wave = one 64x64 upper-triangle tile
// (2080 tiles, 520 blocks x 4 waves); fused stats + last-block finalize.
// R5 fix: R3/R4 were SPILL-CRIPPLED -- VGPR_Count 96/100 vs ~200 demand,
// WRITE_SIZE 5.3 MB == scratch spill traffic, all pipes <7% busy.
// __launch_bounds__(256, 2) lifts the cap to 256 VGPRs/wave (2 waves/EU,
// which is all our grid supplies anyway) -> no spills.
//
// CmF layout: shorts, index = ((band*8 + k)*4 + rt)*512 + (l15*4+quad)*8 + j
// Fragment load for (band, k, rt): lanes read one contiguous 1 KB chunk.

#define BSZ   2048
#define NROW  4096
#define DDIM  256
#define INVT  (1.0f / 0.07f)
#define NB64  64                       // 4096/64 bands
#define NT2   (NB64 * (NB64 + 1) / 2)  // 2080 upper-triangle 64x64 tiles
#define TPB   4                        // tiles (waves) per block
#define NBLK  (NT2 / TPB)              // 520 blocks

typedef __attribute__((ext_vector_type(8))) __bf16 bf16x8;
typedef __attribute__((ext_vector_type(4))) float f32x4;

__device__ __forceinline__ short f2bs(float x) {
    __bf16 b = (__bf16)x;
    return __builtin_bit_cast(short, b);
}
__device__ __forceinline__ void ag_store(float* p, float v) {
    __hip_atomic_store(p, v, __ATOMIC_RELAXED, __HIP_MEMORY_SCOPE_AGENT);
}
__device__ __forceinline__ float ag_load(const float* p) {
    return __hip_atomic_load(p, __ATOMIC_RELAXED, __HIP_MEMORY_SCOPE_AGENT);
}

// contrast row i = v*B + b  ->  features row b*V + v  (fp32, 256 elems)
__device__ __forceinline__ const float* crow_ptr(const float* feats, int i) {
    return feats + (((i & (BSZ - 1)) * 2 + (i >> 11)) << 8);
}

// ---------------- prep: frag-major bf16 pack, self-dots, zero E/W/cnt ------
__global__ __launch_bounds__(256) void prep_kernel(const float* __restrict__ feats,
        float* __restrict__ selfdot, float* __restrict__ EWzero,
        int* __restrict__ cnt, short* __restrict__ CmF) {
    int tid = threadIdx.x;
    int z = blockIdx.x * 256 + tid;
    if (z < 2 * NROW) EWzero[z] = 0.0f;                  // zero E and W
    if (z == 0) __hip_atomic_store(cnt, 0, __ATOMIC_RELAXED, __HIP_MEMORY_SCOPE_AGENT);

    // --- part A: self-dot, one wave per row (1024 blocks x 4 waves) ---
    int lane = tid & 63;
    int row  = (blockIdx.x << 2) + (tid >> 6);
    const float4* src = (const float4*)crow_ptr(feats, row);
    float4 v = src[lane];
    float a0 = (float)(__bf16)v.x, a1 = (float)(__bf16)v.y;
    float a2 = (float)(__bf16)v.z, a3 = (float)(__bf16)v.w;
    float s = a0 * a0 + a1 * a1 + a2 * a2 + a3 * a3;     // self-dot of bf16 row
    #pragma unroll
    for (int off = 32; off; off >>= 1) s += __shfl_xor(s, off, 64);
    if (lane == 0) selfdot[row] = s;

    // --- part B: fragment-major pack; gid covers 2M shorts / 8 per thread ---
    int gid  = z;                    // 0..262143
    int quad = gid & 3;
    int l15  = (gid >> 2) & 15;
    int rt   = (gid >> 6) & 3;
    int k    = (gid >> 8) & 7;
    int b    = gid >> 12;
    int srow = (b << 6) + (rt << 4) + l15;
    int kel  = (k << 5) + (quad << 3);
    const float4* fp = (const float4*)(crow_ptr(feats, srow) + kel);
    float4 v0 = fp[0], v1 = fp[1];
    short h[8] = { f2bs(v0.x), f2bs(v0.y), f2bs(v0.z), f2bs(v0.w),
                   f2bs(v1.x), f2bs(v1.y), f2bs(v1.z), f2bs(v1.w) };
    *(int4*)(CmF + gid * 8) = *(int4*)h;
}

// ---------------- barrier-free symmetric GEMM + stats + finalize -----------
__global__ __launch_bounds__(256, 2) void gemm_sym(const short* __restrict__ CmF,
        const float* __restrict__ selfdot, float* __restrict__ E,
        float* __restrict__ W, float* __restrict__ Lpos, int* __restrict__ cnt,
        const int* __restrict__ index, const float* __restrict__ u,
        float* __restrict__ out) {
    int tid  = threadIdx.x;
    int wave = tid >> 6;
    int lane = tid & 63;
    int quad = lane >> 4;
    int l15  = lane & 15;

    // one wave = one tile; triangle decode t -> (p,q), p>=q
    int t = blockIdx.x * TPB + wave;
    int p = (int)((sqrtf(8.0f * (float)t + 1.0f) - 1.0f) * 0.5f);
    while ((p + 1) * (p + 2) / 2 <= t) ++p;
    while (p * (p + 1) / 2 > t) --p;
    int q = t - p * (p + 1) / 2;
    int rowBase = q << 6;            // row band (64)
    int colBase = p << 6;            // col band, >= row band
    bool offdiag = (p != q);

    const short* aB = CmF + q * 16384 + ((l15 << 2) + quad) * 8;
    const short* bB = CmF + p * 16384 + ((l15 << 2) + quad) * 8;

    f32x4 acc[4][4];
    #pragma unroll
    for (int a = 0; a < 4; ++a)
        #pragma unroll
        for (int c = 0; c < 4; ++c) acc[a][c] = (f32x4){0.f, 0.f, 0.f, 0.f};

    bf16x8 aC[4], bC[4];
    #pragma unroll
    for (int rt = 0; rt < 4; ++rt) aC[rt] = *(const bf16x8*)(aB + rt * 512);
    #pragma unroll
    for (int ct = 0; ct < 4; ++ct) bC[ct] = *(const bf16x8*)(bB + ct * 512);

    #pragma unroll
    for (int k = 0; k < 8; ++k) {
        bf16x8 aN[4], bN[4];
        if (k < 7) {                 // prefetch next k-step (no barrier)
            #pragma unroll
            for (int rt = 0; rt < 4; ++rt)
                aN[rt] = *(const bf16x8*)(aB + ((k + 1) * 4 + rt) * 512);
            #pragma unroll
            for (int ct = 0; ct < 4; ++ct)
                bN[ct] = *(const bf16x8*)(bB + ((k + 1) * 4 + ct) * 512);
        }
        #pragma unroll
        for (int rt = 0; rt < 4; ++rt)
            #pragma unroll
            for (int ct = 0; ct < 4; ++ct)
                acc[rt][ct] = __builtin_amdgcn_mfma_f32_16x16x32_bf16(
                    aC[rt], bC[ct], acc[rt][ct], 0, 0, 0);
        if (k < 7) {
            #pragma unroll
            for (int rt = 0; rt < 4; ++rt) aC[rt] = aN[rt];
            #pragma unroll
            for (int ct = 0; ct < 4; ++ct) bC[ct] = bN[ct];
        }
    }

    // ---- epilogue: C/D layout col = lane&15, row = quad*4 + reg  [m89/m91]
    float sdr[4][4];
    #pragma unroll
    for (int rt = 0; rt < 4; ++rt)
        #pragma unroll
        for (int r = 0; r < 4; ++r)
            sdr[rt][r] = selfdot[rowBase + rt * 16 + (quad << 2) + r];
    float sdc[4];
    #pragma unroll
    for (int ct = 0; ct < 4; ++ct)
        sdc[ct] = selfdot[colBase + ct * 16 + l15];

    float Ep[4][4] = {}, Wp[4][4] = {};
    float Ec[4] = {}, Wc[4] = {};
    #pragma unroll
    for (int rt = 0; rt < 4; ++rt) {
        #pragma unroll
        for (int ct = 0; ct < 4; ++ct) {
            int gcol = colBase + ct * 16 + l15;
            #pragma unroll
            for (int r = 0; r < 4; ++r) {
                int grow = rowBase + rt * 16 + (quad << 2) + r;
                float d = acc[rt][ct][r];
                float l = (d - sdr[rt][r]) * INVT;       // row-view logit
                float e = __expf(l);
                Ep[rt][r] += e;
                Wp[rt][r] += e * l;
                if (gcol == (grow ^ BSZ)) ag_store(&Lpos[grow], l);
                if (offdiag) {
                    float l2 = (d - sdc[ct]) * INVT;     // col-view logit
                    float e2 = __expf(l2);
                    Ec[ct] += e2;
                    Wc[ct] += e2 * l2;
                    if (grow == (gcol ^ BSZ)) ag_store(&Lpos[gcol], l2);
                }
            }
        }
    }
    // row-path: reduce over 16 l15 lanes per row, 1-lane atomic per row
    #pragma unroll
    for (int rt = 0; rt < 4; ++rt) {
        #pragma unroll
        for (int r = 0; r < 4; ++r) {
            float e = Ep[rt][r], w = Wp[rt][r];
            #pragma unroll
            for (int off = 1; off < 16; off <<= 1) {
                e += __shfl_xor(e, off, 64);
                w += __shfl_xor(w, off, 64);
            }
            if (l15 == 0) {
                int grow = rowBase + rt * 16 + (quad << 2) + r;
                atomicAdd(&E[grow], e);
                atomicAdd(&W[grow], w);
            }
        }
    }
    // col-path: reduce over 4 quads per col, 16-lane atomic
    if (offdiag) {
        #pragma unroll
        for (int ct = 0; ct < 4; ++ct) {
            float e = Ec[ct], w = Wc[ct];
            e += __shfl_xor(e, 16, 64);  w += __shfl_xor(w, 16, 64);
            e += __shfl_xor(e, 32, 64);  w += __shfl_xor(w, 32, 64);
            if (quad == 0) {
                int gcol = colBase + ct * 16 + l15;
                atomicAdd(&E[gcol], e);
                atomicAdd(&W[gcol], w);
            }
        }
    }

    // ---- last-block ticket: fused finalize ----
    __shared__ int isLast;
    __threadfence();                 // release our E/W/Lpos writes
    __syncthreads();
    if (tid == 0) isLast = (atomicAdd(cnt, 1) == NBLK - 1);
    __syncthreads();
    if (!isLast) return;
    __threadfence();                 // acquire all blocks' writes

    __shared__ float unew[BSZ];
    for (int b = tid; b < BSZ; b += 256) {
        float lp = ag_load(&Lpos[b]);
        unew[b] = 0.1f * u[index[b]] + 0.9f * (ag_load(&E[b]) - __expf(lp));
    }
    __syncthreads();
    float local = 0.0f;
    for (int i = tid; i < NROW; i += 256) {
        float lp  = ag_load(&Lpos[i]);
        float elp = __expf(lp);
        local += lp - (ag_load(&W[i]) - elp * lp) / unew[i & (BSZ - 1)];
    }
    #pragma unroll
    for (int off = 32; off; off >>= 1) local += __shfl_xor(local, off, 64);
    __shared__ float part[4];
    if (lane == 0) part[wave] = local;
    __syncthreads();
    if (tid == 0) out[0] = -(part[0] + part[1] + part[2] + part[3]) / (float)NROW;
}

extern "C" void kernel_launch(void* const* d_in, const int* in_sizes, int n_in,
                              void* d_out, int out_size, void* d_ws, size_t ws_size,
                              hipStream_t stream) {
    const int*   index = (const int*)d_in[0];
    const float* feats = (const float*)d_in[1];
    const float* u     = (const float*)d_in[2];
    float* out = (float*)d_out;

    // ws: [selfdot|E|W|Lpos] (4x4096 f32 = 64 KB) | cnt | ... | CmF @128KB
    float* selfdot = (float*)d_ws;
    float* E    = selfdot + NROW;
    float* W    = E + NROW;
    float* Lpos = W + NROW;
    int*   cnt  = (int*)(Lpos + NROW);                   // byte 65536
    short* CmF  = (short*)((char*)d_ws + 131072);        // byte 131072, 2 MB

    prep_kernel<<<1024, 256, 0, stream>>>(feats, selfdot, E, cnt, CmF);
    gemm_sym<<<NBLK, 256, 0, stream>>>(CmF, selfdot, E, W, Lpos, cnt, index, u, out);
}

// Round 6
// 116.211 us; speedup vs baseline: 1.3640x; 1.2730x over previous
//
#include <hip/hip_runtime.h>

// BatchIndependentLoss: SupCon-style loss, B=2048, V=2, D=256, N=4096.
// loss = -mean_i( lp_i - (W_i - e^{lp}*lp) / u_new[i%B] )
// Structure: NO LDS/barriers in GEMM K-loop; 2 MB frag-major bf16 operand
// (L2-resident); one wave = one 64x64 upper-triangle tile (2080 tiles,
// 520 blocks x 4 waves); row+col (transposed) stats from each tile.
// R6 fix: R3/R4/R5 were FENCE-BOUND, not spill-bound -- the last-block
// ticket's per-block __threadfence() forces a bulk L2 writeback+inv per
// block (XCD L2s non-coherent -> agent fence = cache maintenance).
// Evidence: WRITE_SIZE identical 5.25 MB across 3 different kernels
// (= residual poison flushed from L2), all pipes <7% busy, ~62-72 us
// regardless of inner loop. Finalize is now its own tiny dispatch; the
// single inter-dispatch flush replaces 520 explicit fences.
//
// CmF layout: shorts, index = ((band*8 + k)*4 + rt)*512 + (l15*4+quad)*8 + j
// Fragment load for (band, k, rt): wave reads one contiguous 1 KB chunk.

#define BSZ   2048
#define NROW  4096
#define DDIM  256
#define INVT  (1.0f / 0.07f)
#define NB64  64                       // 4096/64 bands
#define NT2   (NB64 * (NB64 + 1) / 2)  // 2080 upper-triangle 64x64 tiles
#define TPB   4                        // tiles (waves) per block
#define NBLK  (NT2 / TPB)              // 520 blocks

typedef __attribute__((ext_vector_type(8))) __bf16 bf16x8;
typedef __attribute__((ext_vector_type(4))) float f32x4;

__device__ __forceinline__ short f2bs(float x) {
    __bf16 b = (__bf16)x;
    return __builtin_bit_cast(short, b);
}

// contrast row i = v*B + b  ->  features row b*V + v  (fp32, 256 elems)
__device__ __forceinline__ const float* crow_ptr(const float* feats, int i) {
    return feats + (((i & (BSZ - 1)) * 2 + (i >> 11)) << 8);
}

// ---------------- prep: frag-major bf16 pack, self-dots, zero E/W ----------
__global__ __launch_bounds__(256) void prep_kernel(const float* __restrict__ feats,
        float* __restrict__ selfdot, float* __restrict__ EWzero,
        short* __restrict__ CmF) {
    int tid = threadIdx.x;
    int z = blockIdx.x * 256 + tid;
    if (z < 2 * NROW) EWzero[z] = 0.0f;                  // zero E and W

    // --- part A: self-dot, one wave per row (1024 blocks x 4 waves) ---
    int lane = tid & 63;
    int row  = (blockIdx.x << 2) + (tid >> 6);
    const float4* src = (const float4*)crow_ptr(feats, row);
    float4 v = src[lane];
    float a0 = (float)(__bf16)v.x, a1 = (float)(__bf16)v.y;
    float a2 = (float)(__bf16)v.z, a3 = (float)(__bf16)v.w;
    float s = a0 * a0 + a1 * a1 + a2 * a2 + a3 * a3;     // self-dot of bf16 row
    #pragma unroll
    for (int off = 32; off; off >>= 1) s += __shfl_xor(s, off, 64);
    if (lane == 0) selfdot[row] = s;

    // --- part B: fragment-major pack; gid covers 2M shorts / 8 per thread ---
    int gid  = z;                    // 0..262143
    int quad = gid & 3;
    int l15  = (gid >> 2) & 15;
    int rt   = (gid >> 6) & 3;
    int k    = (gid >> 8) & 7;
    int b    = gid >> 12;
    int srow = (b << 6) + (rt << 4) + l15;
    int kel  = (k << 5) + (quad << 3);
    const float4* fp = (const float4*)(crow_ptr(feats, srow) + kel);
    float4 v0 = fp[0], v1 = fp[1];
    short h[8] = { f2bs(v0.x), f2bs(v0.y), f2bs(v0.z), f2bs(v0.w),
                   f2bs(v1.x), f2bs(v1.y), f2bs(v1.z), f2bs(v1.w) };
    *(int4*)(CmF + gid * 8) = *(int4*)h;
}

// ---------------- barrier-free symmetric GEMM + stats ----------------------
__global__ __launch_bounds__(256, 2) void gemm_sym(const short* __restrict__ CmF,
        const float* __restrict__ selfdot, float* __restrict__ E,
        float* __restrict__ W, float* __restrict__ Lpos) {
    int tid  = threadIdx.x;
    int wave = tid >> 6;
    int lane = tid & 63;
    int quad = lane >> 4;
    int l15  = lane & 15;

    // one wave = one tile; triangle decode t -> (p,q), p>=q
    int t = blockIdx.x * TPB + wave;
    int p = (int)((sqrtf(8.0f * (float)t + 1.0f) - 1.0f) * 0.5f);
    while ((p + 1) * (p + 2) / 2 <= t) ++p;
    while (p * (p + 1) / 2 > t) --p;
    int q = t - p * (p + 1) / 2;
    int rowBase = q << 6;            // row band (64)
    int colBase = p << 6;            // col band, >= row band
    bool offdiag = (p != q);

    const short* aB = CmF + q * 16384 + ((l15 << 2) + quad) * 8;
    const short* bB = CmF + p * 16384 + ((l15 << 2) + quad) * 8;

    f32x4 acc[4][4];
    #pragma unroll
    for (int a = 0; a < 4; ++a)
        #pragma unroll
        for (int c = 0; c < 4; ++c) acc[a][c] = (f32x4){0.f, 0.f, 0.f, 0.f};

    bf16x8 aC[4], bC[4];
    #pragma unroll
    for (int rt = 0; rt < 4; ++rt) aC[rt] = *(const bf16x8*)(aB + rt * 512);
    #pragma unroll
    for (int ct = 0; ct < 4; ++ct) bC[ct] = *(const bf16x8*)(bB + ct * 512);

    #pragma unroll
    for (int k = 0; k < 8; ++k) {
        bf16x8 aN[4], bN[4];
        if (k < 7) {                 // prefetch next k-step (no barrier)
            #pragma unroll
            for (int rt = 0; rt < 4; ++rt)
                aN[rt] = *(const bf16x8*)(aB + ((k + 1) * 4 + rt) * 512);
            #pragma unroll
            for (int ct = 0; ct < 4; ++ct)
                bN[ct] = *(const bf16x8*)(bB + ((k + 1) * 4 + ct) * 512);
        }
        #pragma unroll
        for (int rt = 0; rt < 4; ++rt)
            #pragma unroll
            for (int ct = 0; ct < 4; ++ct)
                acc[rt][ct] = __builtin_amdgcn_mfma_f32_16x16x32_bf16(
                    aC[rt], bC[ct], acc[rt][ct], 0, 0, 0);
        if (k < 7) {
            #pragma unroll
            for (int rt = 0; rt < 4; ++rt) aC[rt] = aN[rt];
            #pragma unroll
            for (int ct = 0; ct < 4; ++ct) bC[ct] = bN[ct];
        }
    }

    // ---- epilogue: C/D layout col = lane&15, row = quad*4 + reg  [m89/m91]
    float sdr[4][4];
    #pragma unroll
    for (int rt = 0; rt < 4; ++rt)
        #pragma unroll
        for (int r = 0; r < 4; ++r)
            sdr[rt][r] = selfdot[rowBase + rt * 16 + (quad << 2) + r];
    float sdc[4];
    #pragma unroll
    for (int ct = 0; ct < 4; ++ct)
        sdc[ct] = selfdot[colBase + ct * 16 + l15];

    float Ep[4][4] = {}, Wp[4][4] = {};
    float Ec[4] = {}, Wc[4] = {};
    #pragma unroll
    for (int rt = 0; rt < 4; ++rt) {
        #pragma unroll
        for (int ct = 0; ct < 4; ++ct) {
            int gcol = colBase + ct * 16 + l15;
            #pragma unroll
            for (int r = 0; r < 4; ++r) {
                int grow = rowBase + rt * 16 + (quad << 2) + r;
                float d = acc[rt][ct][r];
                float l = (d - sdr[rt][r]) * INVT;       // row-view logit
                float e = __expf(l);
                Ep[rt][r] += e;
                Wp[rt][r] += e * l;
                if (gcol == (grow ^ BSZ)) Lpos[grow] = l;
                if (offdiag) {
                    float l2 = (d - sdc[ct]) * INVT;     // col-view logit
                    float e2 = __expf(l2);
                    Ec[ct] += e2;
                    Wc[ct] += e2 * l2;
                    if (grow == (gcol ^ BSZ)) Lpos[gcol] = l2;
                }
            }
        }
    }
    // row-path: reduce over 16 l15 lanes per row, 1-lane atomic per row
    #pragma unroll
    for (int rt = 0; rt < 4; ++rt) {
        #pragma unroll
        for (int r = 0; r < 4; ++r) {
            float e = Ep[rt][r], w = Wp[rt][r];
            #pragma unroll
            for (int off = 1; off < 16; off <<= 1) {
                e += __shfl_xor(e, off, 64);
                w += __shfl_xor(w, off, 64);
            }
            if (l15 == 0) {
                int grow = rowBase + rt * 16 + (quad << 2) + r;
                atomicAdd(&E[grow], e);
                atomicAdd(&W[grow], w);
            }
        }
    }
    // col-path: reduce over 4 quads per col, 16-lane atomic
    if (offdiag) {
        #pragma unroll
        for (int ct = 0; ct < 4; ++ct) {
            float e = Ec[ct], w = Wc[ct];
            e += __shfl_xor(e, 16, 64);  w += __shfl_xor(w, 16, 64);
            e += __shfl_xor(e, 32, 64);  w += __shfl_xor(w, 32, 64);
            if (quad == 0) {
                int gcol = colBase + ct * 16 + l15;
                atomicAdd(&E[gcol], e);
                atomicAdd(&W[gcol], w);
            }
        }
    }
    // NO ticket, NO __threadfence: visibility to the finalize dispatch is
    // provided by the kernel-boundary release/acquire (one flush, not 520).
}

// ---------------- finalize: u_new + scalar reduction -----------------------
__global__ __launch_bounds__(1024) void finalize_kernel(const int* __restrict__ index,
        const float* __restrict__ u, const float* __restrict__ E,
        const float* __restrict__ W, const float* __restrict__ Lpos,
        float* __restrict__ out) {
    __shared__ float unew[BSZ];
    __shared__ float partial[16];
    int tid = threadIdx.x;
    for (int b = tid; b < BSZ; b += 1024) {
        float lp = Lpos[b];
        unew[b] = 0.1f * u[index[b]] + 0.9f * (E[b] - __expf(lp));
    }
    __syncthreads();
    float local = 0.0f;
    for (int i = tid; i < NROW; i += 1024) {
        float lp  = Lpos[i];
        float elp = __expf(lp);
        local += lp - (W[i] - elp * lp) / unew[i & (BSZ - 1)];
    }
    #pragma unroll
    for (int off = 32; off; off >>= 1) local += __shfl_xor(local, off, 64);
    if ((tid & 63) == 0) partial[tid >> 6] = local;
    __syncthreads();
    if (tid == 0) {
        float s = 0.0f;
        #pragma unroll
        for (int w = 0; w < 16; ++w) s += partial[w];
        out[0] = -s / (float)NROW;
    }
}

extern "C" void kernel_launch(void* const* d_in, const int* in_sizes, int n_in,
                              void* d_out, int out_size, void* d_ws, size_t ws_size,
                              hipStream_t stream) {
    const int*   index = (const int*)d_in[0];
    const float* feats = (const float*)d_in[1];
    const float* u     = (const float*)d_in[2];
    float* out = (float*)d_out;

    // ws: [selfdot|E|W|Lpos] (4x4096 f32 = 64 KB) | ... | CmF @128KB (2 MB)
    float* selfdot = (float*)d_ws;
    float* E    = selfdot + NROW;
    float* W    = E + NROW;
    float* Lpos = W + NROW;
    short* CmF  = (short*)((char*)d_ws + 131072);

    prep_kernel<<<1024, 256, 0, stream>>>(feats, selfdot, E, CmF);
    gemm_sym<<<NBLK, 256, 0, stream>>>(CmF, selfdot, E, W, Lpos);
    finalize_kernel<<<1, 1024, 0, stream>>>(index, u, E, W, Lpos, out);
}